// Round 11
// baseline (278.539 us; speedup 1.0000x reference)
//
#include <hip/hip_runtime.h>
#include <hip/hip_bf16.h>
#include <math.h>

#define DD 128

typedef __attribute__((ext_vector_type(8))) short bf16x8;
typedef __attribute__((ext_vector_type(4))) float f32x4;

static __device__ __forceinline__ short f2bf(float x) {
    union { float f; unsigned u; } v; v.f = x;
    unsigned r = v.u + 0x7FFFu + ((v.u >> 16) & 1u);   // RNE
    return (short)(r >> 16);
}
static __device__ __forceinline__ float bf2f(unsigned short h) {
    union { unsigned u; float f; } v; v.u = ((unsigned)h) << 16;
    return v.f;
}
// pack 2 f32 -> 2 bf16 (RNE), dst = bf(lo) | bf(hi)<<16
static __device__ __forceinline__ unsigned cvtpk(float lo, float hi) {
    unsigned r;
    asm("v_cvt_pk_bf16_f32 %0, %1, %2" : "=v"(r) : "v"(lo), "v"(hi));
    return r;
}

// ---------------- K0: block 0 = prefix scan; blocks 1..64 = WuT bf16 prep ----------------
__global__ void k0_combined(const int* __restrict__ counts, int* __restrict__ offs, int B,
                            const float* __restrict__ Wu, short* __restrict__ wuT)
{
    if (blockIdx.x == 0) {
        __shared__ int part[256];
        int t = threadIdx.x;
        int chunk = (B + 255) >> 8;
        int s = 0;
        for (int i = 0; i < chunk; ++i) {
            int idx = t * chunk + i;
            if (idx < B) s += counts[idx];
        }
        part[t] = s;
        __syncthreads();
        for (int off = 1; off < 256; off <<= 1) {
            int val = (t >= off) ? part[t - off] : 0;
            __syncthreads();
            part[t] += val;
            __syncthreads();
        }
        int run = (t > 0) ? part[t - 1] : 0;
        for (int i = 0; i < chunk; ++i) {
            int idx = t * chunk + i;
            if (idx < B) { offs[idx] = run; run += counts[idx]; }
        }
    } else {
        int idx = (blockIdx.x - 1) * 256 + threadIdx.x;   // 0..16383
        int h = idx >> 7, k = idx & 127;
        wuT[(size_t)h * DD + k] = f2bf(Wu[(size_t)k * DD + h]);
    }
}

// ---------------- K1: per-graph mean + absmax (float4 lanes, 8-row stripe) ----------------
__global__ __launch_bounds__(256)
void k1_stats(const float* __restrict__ feats, const int* __restrict__ offs,
              const int* __restrict__ counts, float* __restrict__ mean,
              float* __restrict__ amax)
{
    int g = blockIdx.x;
    int s = offs[g], c = counts[g];
    int t = threadIdx.x;
    int col = (t & 31) * 4;          // float4 column
    int r0 = t >> 5;                 // 0..7
    float4 sm = {0.f, 0.f, 0.f, 0.f};
    float4 mx = {0.f, 0.f, 0.f, 0.f};
    const float* base = feats + (size_t)s * DD + col;
    #pragma unroll 4
    for (int i = r0; i < c; i += 8) {
        float4 v = *(const float4*)(base + (size_t)i * DD);
        sm.x += v.x; sm.y += v.y; sm.z += v.z; sm.w += v.w;
        mx.x = fmaxf(mx.x, fabsf(v.x)); mx.y = fmaxf(mx.y, fabsf(v.y));
        mx.z = fmaxf(mx.z, fabsf(v.z)); mx.w = fmaxf(mx.w, fabsf(v.w));
    }
    __shared__ float ls[8][DD];
    __shared__ float lm[8][DD];
    *(float4*)&ls[r0][col] = sm;
    *(float4*)&lm[r0][col] = mx;
    __syncthreads();
    if (t < DD) {
        float ss = 0.f, mm = 0.f;
        #pragma unroll
        for (int r = 0; r < 8; ++r) {
            ss += ls[r][t];
            mm = fmaxf(mm, lm[r][t]);
        }
        mean[(size_t)g * DD + t] = ss / (float)c;
        amax[(size_t)g * DD + t] = mm;
    }
}

// ---------------- K2: vtab[g] = row(g) @ W_v + b_v ----------------
// row(g) = (g odd) ? amax[g/2] : mean[g/2]   (torch interleaved-table quirk)
__global__ __launch_bounds__(128)
void k2_vtab(const float* __restrict__ mean, const float* __restrict__ amax,
             const float* __restrict__ Wv, const float* __restrict__ bv,
             float* __restrict__ vtab, int B)
{
    __shared__ float rows[16][DD];
    int g0 = blockIdx.x * 16;
    int h = threadIdx.x;
    for (int i = 0; i < 16; ++i) {
        int g = g0 + i;
        float val = 0.f;
        if (g < B) {
            int gg = g >> 1;
            const float* src = (g & 1) ? &amax[(size_t)gg * DD] : &mean[(size_t)gg * DD];
            val = src[h];
        }
        rows[i][h] = val;
    }
    __syncthreads();
    float acc[16];
    float bvh = bv[h];
    #pragma unroll
    for (int i = 0; i < 16; ++i) acc[i] = bvh;
    for (int d = 0; d < DD; d += 2) {
        float w0 = Wv[(size_t)d * DD + h];
        float w1 = Wv[(size_t)(d + 1) * DD + h];
        #pragma unroll
        for (int i = 0; i < 16; ++i) {
            float2 r = *(const float2*)&rows[i][d];
            acc[i] = fmaf(r.x, w0, acc[i]);
            acc[i] = fmaf(r.y, w1, acc[i]);
        }
    }
    #pragma unroll
    for (int i = 0; i < 16; ++i) {
        int g = g0 + i;
        if (g < B) vtab[(size_t)g * DD + h] = acc[i];
    }
}

// ---------------- KC: flat fused GEMM + logit + graph-parallel pooling ----------------
// 128 nodes/block, compile-time loops. Pooling: wave w handles graphs
// gfirst+w, gfirst+w+4, ... ; graphs fully inside the block write out[] directly,
// boundary-crossing graphs (span <=2 blocks since c<=126) write partial slot 0/1.
__global__ __launch_bounds__(256, 4)
void kc_flat2(const float* __restrict__ feats, const short* __restrict__ wuT,
              const float* __restrict__ vtab, const float* __restrict__ we,
              const int* __restrict__ seg, const int* __restrict__ offs,
              const int* __restrict__ counts,
              float* __restrict__ partial, float* __restrict__ dens,
              float* __restrict__ out, int N)
{
    __shared__ short fe[128 * DD];   // 32 KB swizzled bf16 [row][128]
    __shared__ float eel[128];
    __shared__ int   segl[128];
    char* feb = (char*)fe;
    const int t = threadIdx.x;
    const int bid = blockIdx.x;
    const int n0 = bid << 7;

    if (t < 128) {
        int n = n0 + t;
        segl[t] = seg[(n < N) ? n : (N - 1)];
    }

    // stage: 2048 x 16B bf16 chunks, 8 per thread, fully unrolled
    #pragma unroll
    for (int it = 0; it < 8; ++it) {
        int ch = it * 256 + t;
        int row = ch >> 4, sub = ch & 15;
        int n = n0 + row;
        uint4 uv;
        if (n < N) {
            const float4* gp = (const float4*)(feats + (size_t)n * DD + sub * 8);
            float4 a = gp[0], b = gp[1];
            uv.x = cvtpk(a.x, a.y);
            uv.y = cvtpk(a.z, a.w);
            uv.z = cvtpk(b.x, b.y);
            uv.w = cvtpk(b.z, b.w);
        } else {
            uv = (uint4){0u, 0u, 0u, 0u};
        }
        *(uint4*)(feb + row * 256 + ((sub * 16) ^ ((row & 7) << 4))) = uv;
    }
    __syncthreads();

    const int w = t >> 6, lane = t & 63;
    const int l15 = lane & 15, kg = lane >> 4;

    {
        float wv[8];
        #pragma unroll
        for (int ht = 0; ht < 8; ++ht) wv[ht] = we[l15 + ht * 16];

        // GEMM + logit: wave w -> node tiles {w, w+4}
        #pragma unroll
        for (int p = 0; p < 2; ++p) {
            const int tb = (w + p * 4) * 16;
            bf16x8 af[4];
            #pragma unroll
            for (int ks = 0; ks < 4; ++ks)
                af[ks] = *(const bf16x8*)(feb + (tb + l15) * 256 +
                                          (((ks * 4 + kg) * 16) ^ ((l15 & 7) << 4)));
            f32x4 acc[8];
            #pragma unroll
            for (int ht = 0; ht < 8; ++ht) acc[ht] = (f32x4){0.f, 0.f, 0.f, 0.f};
            #pragma unroll
            for (int ks = 0; ks < 4; ++ks) {
                #pragma unroll
                for (int ht = 0; ht < 8; ++ht) {
                    bf16x8 bfr = *(const bf16x8*)(wuT + (size_t)(l15 + ht * 16) * DD + ks * 32 + kg * 8);
                    acc[ht] = __builtin_amdgcn_mfma_f32_16x16x32_bf16(af[ks], bfr, acc[ht], 0, 0, 0);
                }
            }
            #pragma unroll
            for (int r = 0; r < 4; ++r) {
                int node = tb + kg * 4 + r;          // C layout: row=(lane>>4)*4+reg
                int gn = segl[node];
                const float* vg = vtab + (size_t)gn * DD + l15;
                float pp = 0.f;
                #pragma unroll
                for (int ht = 0; ht < 8; ++ht) {
                    float x = acc[ht][r] + vg[ht * 16];
                    float sg = 1.f / (1.f + __expf(-x));
                    pp = fmaf(sg, wv[ht], pp);
                }
                pp += __shfl_xor(pp, 1);
                pp += __shfl_xor(pp, 2);
                pp += __shfl_xor(pp, 4);
                pp += __shfl_xor(pp, 8);
                if (l15 == 0)
                    eel[node] = (n0 + node < N) ? ((pp != 0.f) ? __expf(pp) : pp) : 0.f;
            }
        }
    }
    __syncthreads();

    // graph-parallel pooling from LDS (bf16 feats, fp32 accum)
    {
        const int gfirst = segl[0];
        const int glast  = segl[127];
        for (int g = gfirst + w; g <= glast; g += 4) {
            int go = offs[g];
            int gc = counts[g];
            int rbeg = go - n0;      rbeg = (rbeg > 0) ? rbeg : 0;
            int rend = go + gc - n0; rend = (rend < 128) ? rend : 128;
            bool complete = (go >= n0) && (go + gc <= n0 + 128);
            float ax = 0.f, ay = 0.f, dw = 0.f;
            for (int i = rbeg; i < rend; ++i) {
                float wi = eel[i];
                unsigned pv = *(const unsigned*)(feb + i * 256 + ((lane * 4) ^ ((i & 7) << 4)));
                dw += wi;
                ax = fmaf(bf2f((unsigned short)(pv & 0xffffu)), wi, ax);
                ay = fmaf(bf2f((unsigned short)(pv >> 16)), wi, ay);
            }
            if (complete) {
                float inv = 1.f / dw;
                *(float2*)&out[(size_t)g * DD + lane * 2] = make_float2(ax * inv, ay * inv);
            } else {
                int slot = (go >= n0) ? 0 : 1;
                *(float2*)&partial[(size_t)(g * 2 + slot) * DD + lane * 2] = make_float2(ax, ay);
                if (lane == 0) dens[g * 2 + slot] = dw;
            }
        }
    }
}

// ---------------- KD: combine the 2 partial slots of boundary-crossing graphs ----------------
__global__ __launch_bounds__(128)
void kd_combine(const float* __restrict__ partial, const float* __restrict__ dens,
                const int* __restrict__ offs, const int* __restrict__ counts,
                float* __restrict__ out, int B)
{
    int g = blockIdx.x;
    int off = offs[g], c = counts[g];
    if ((off >> 7) == ((off + c - 1) >> 7)) return;   // interior: already written by kc
    int d = threadIdx.x;
    float v = partial[(size_t)(g * 2) * DD + d] + partial[(size_t)(g * 2 + 1) * DD + d];
    float den = dens[g * 2] + dens[g * 2 + 1];
    out[(size_t)g * DD + d] = v / den;
}

extern "C" void kernel_launch(void* const* d_in, const int* in_sizes, int n_in,
                              void* d_out, int out_size, void* d_ws, size_t ws_size,
                              hipStream_t stream)
{
    const float* feats  = (const float*)d_in[0];
    const float* Wu     = (const float*)d_in[1];
    const float* Wv     = (const float*)d_in[2];
    const float* bv     = (const float*)d_in[3];
    const float* we     = (const float*)d_in[4];
    const int*   seg    = (const int*)d_in[5];
    const int*   counts = (const int*)d_in[6];
    const int N = in_sizes[0] / DD;
    const int B = in_sizes[6];

    char* w = (char*)d_ws;
    int*   offs = (int*)w;    w += ((size_t)B * sizeof(int) + 255) & ~(size_t)255;
    float* mean = (float*)w;  w += (size_t)B * DD * sizeof(float);
    float* amax = (float*)w;  w += (size_t)B * DD * sizeof(float);
    float* vtab = (float*)w;  w += (size_t)B * DD * sizeof(float);
    short* wuT  = (short*)w;  w += (size_t)DD * DD * sizeof(short);
    float* dens = (float*)w;  w += (size_t)B * 2 * sizeof(float);
    // partial pooled vectors alias mean+amax (dead after k2): 2*B*DD floats
    float* partial = mean;

    k0_combined<<<65, 256, 0, stream>>>(counts, offs, B, Wu, wuT);
    k1_stats<<<B, 256, 0, stream>>>(feats, offs, counts, mean, amax);
    k2_vtab<<<(B + 15) / 16, 128, 0, stream>>>(mean, amax, Wv, bv, vtab, B);

    const int blocks = (N + 127) / 128;
    kc_flat2<<<blocks, 256, 0, stream>>>(feats, wuT, vtab, we, seg, offs, counts,
                                         partial, dens, (float*)d_out, N);
    kd_combine<<<B, 128, 0, stream>>>(partial, dens, offs, counts, (float*)d_out, B);
}

// Round 12
// 273.813 us; speedup vs baseline: 1.0173x; 1.0173x over previous
//
#include <hip/hip_runtime.h>
#include <hip/hip_bf16.h>
#include <math.h>

#define DD 128

typedef __attribute__((ext_vector_type(8))) short bf16x8;
typedef __attribute__((ext_vector_type(4))) float f32x4;

static __device__ __forceinline__ short f2bf(float x) {
    union { float f; unsigned u; } v; v.f = x;
    unsigned r = v.u + 0x7FFFu + ((v.u >> 16) & 1u);   // RNE
    return (short)(r >> 16);
}
static __device__ __forceinline__ float bf2f(unsigned short h) {
    union { unsigned u; float f; } v; v.u = ((unsigned)h) << 16;
    return v.f;
}
// pack 2 f32 -> 2 bf16 (RNE), dst = bf(lo) | bf(hi)<<16
static __device__ __forceinline__ unsigned cvtpk(float lo, float hi) {
    unsigned r;
    asm("v_cvt_pk_bf16_f32 %0, %1, %2" : "=v"(r) : "v"(lo), "v"(hi));
    return r;
}

// ---------------- K0: block 0 = prefix scan; blocks 1..64 = WuT bf16 prep ----------------
__global__ void k0_combined(const int* __restrict__ counts, int* __restrict__ offs, int B,
                            const float* __restrict__ Wu, short* __restrict__ wuT)
{
    if (blockIdx.x == 0) {
        __shared__ int part[256];
        int t = threadIdx.x;
        int chunk = (B + 255) >> 8;
        int s = 0;
        for (int i = 0; i < chunk; ++i) {
            int idx = t * chunk + i;
            if (idx < B) s += counts[idx];
        }
        part[t] = s;
        __syncthreads();
        for (int off = 1; off < 256; off <<= 1) {
            int val = (t >= off) ? part[t - off] : 0;
            __syncthreads();
            part[t] += val;
            __syncthreads();
        }
        int run = (t > 0) ? part[t - 1] : 0;
        for (int i = 0; i < chunk; ++i) {
            int idx = t * chunk + i;
            if (idx < B) { offs[idx] = run; run += counts[idx]; }
        }
    } else {
        int idx = (blockIdx.x - 1) * 256 + threadIdx.x;   // 0..16383
        int h = idx >> 7, k = idx & 127;
        wuT[(size_t)h * DD + k] = f2bf(Wu[(size_t)k * DD + h]);
    }
}

// ---------------- K1: per-graph mean + absmax (float4 lanes, 8-row stripe) ----------------
__global__ __launch_bounds__(256)
void k1_stats(const float* __restrict__ feats, const int* __restrict__ offs,
              const int* __restrict__ counts, float* __restrict__ mean,
              float* __restrict__ amax)
{
    int g = blockIdx.x;
    int s = offs[g], c = counts[g];
    int t = threadIdx.x;
    int col = (t & 31) * 4;          // float4 column
    int r0 = t >> 5;                 // 0..7
    float4 sm = {0.f, 0.f, 0.f, 0.f};
    float4 mx = {0.f, 0.f, 0.f, 0.f};
    const float* base = feats + (size_t)s * DD + col;
    #pragma unroll 4
    for (int i = r0; i < c; i += 8) {
        float4 v = *(const float4*)(base + (size_t)i * DD);
        sm.x += v.x; sm.y += v.y; sm.z += v.z; sm.w += v.w;
        mx.x = fmaxf(mx.x, fabsf(v.x)); mx.y = fmaxf(mx.y, fabsf(v.y));
        mx.z = fmaxf(mx.z, fabsf(v.z)); mx.w = fmaxf(mx.w, fabsf(v.w));
    }
    __shared__ float ls[8][DD];
    __shared__ float lm[8][DD];
    *(float4*)&ls[r0][col] = sm;
    *(float4*)&lm[r0][col] = mx;
    __syncthreads();
    if (t < DD) {
        float ss = 0.f, mm = 0.f;
        #pragma unroll
        for (int r = 0; r < 8; ++r) {
            ss += ls[r][t];
            mm = fmaxf(mm, lm[r][t]);
        }
        mean[(size_t)g * DD + t] = ss / (float)c;
        amax[(size_t)g * DD + t] = mm;
    }
}

// ---------------- K2: vtab[g] = row(g) @ W_v + b_v ----------------
// row(g) = (g odd) ? amax[g/2] : mean[g/2]   (torch interleaved-table quirk)
__global__ __launch_bounds__(128)
void k2_vtab(const float* __restrict__ mean, const float* __restrict__ amax,
             const float* __restrict__ Wv, const float* __restrict__ bv,
             float* __restrict__ vtab, int B)
{
    __shared__ float rows[16][DD];
    int g0 = blockIdx.x * 16;
    int h = threadIdx.x;
    for (int i = 0; i < 16; ++i) {
        int g = g0 + i;
        float val = 0.f;
        if (g < B) {
            int gg = g >> 1;
            const float* src = (g & 1) ? &amax[(size_t)gg * DD] : &mean[(size_t)gg * DD];
            val = src[h];
        }
        rows[i][h] = val;
    }
    __syncthreads();
    float acc[16];
    float bvh = bv[h];
    #pragma unroll
    for (int i = 0; i < 16; ++i) acc[i] = bvh;
    for (int d = 0; d < DD; d += 2) {
        float w0 = Wv[(size_t)d * DD + h];
        float w1 = Wv[(size_t)(d + 1) * DD + h];
        #pragma unroll
        for (int i = 0; i < 16; ++i) {
            float2 r = *(const float2*)&rows[i][d];
            acc[i] = fmaf(r.x, w0, acc[i]);
            acc[i] = fmaf(r.y, w1, acc[i]);
        }
    }
    #pragma unroll
    for (int i = 0; i < 16; ++i) {
        int g = g0 + i;
        if (g < B) vtab[(size_t)g * DD + h] = acc[i];
    }
}

// ---------------- KC: flat fused GEMM + logit + graph-parallel pooling ----------------
// 128 nodes/block, 512 threads (8 waves, ONE 16-node MFMA tile each).
// Pooling loop kept byte-identical to the verified r11 serial form (only the
// wave stride changes 4 -> 8). Graphs span <=2 blocks (c<=126<128): interior
// graphs write out[] directly, crossing graphs write partial slot 0/1.
__global__ __launch_bounds__(512, 8)
void kc_v4(const float* __restrict__ feats, const short* __restrict__ wuT,
           const float* __restrict__ vtab, const float* __restrict__ we,
           const int* __restrict__ seg, const int* __restrict__ offs,
           const int* __restrict__ counts,
           float* __restrict__ partial, float* __restrict__ dens,
           float* __restrict__ out, int N)
{
    __shared__ short fe[128 * DD];   // 32 KB swizzled bf16 [row][128]
    __shared__ float eel[128];
    __shared__ int   segl[128];
    char* feb = (char*)fe;
    const int t = threadIdx.x;
    const int bid = blockIdx.x;
    const int n0 = bid << 7;

    if (t < 128) {
        int n = n0 + t;
        segl[t] = seg[(n < N) ? n : (N - 1)];
    }

    // stage: 2048 x 16B bf16 chunks, 4 per thread, fully unrolled
    #pragma unroll
    for (int it = 0; it < 4; ++it) {
        int ch = it * 512 + t;
        int row = ch >> 4, sub = ch & 15;
        int n = n0 + row;
        uint4 uv;
        if (n < N) {
            const float4* gp = (const float4*)(feats + (size_t)n * DD + sub * 8);
            float4 a = gp[0], b = gp[1];
            uv.x = cvtpk(a.x, a.y);
            uv.y = cvtpk(a.z, a.w);
            uv.z = cvtpk(b.x, b.y);
            uv.w = cvtpk(b.z, b.w);
        } else {
            uv = (uint4){0u, 0u, 0u, 0u};
        }
        *(uint4*)(feb + row * 256 + ((sub * 16) ^ ((row & 7) << 4))) = uv;
    }
    __syncthreads();

    const int w = t >> 6, lane = t & 63;
    const int l15 = lane & 15, kg = lane >> 4;

    {
        float wv[8];
        #pragma unroll
        for (int ht = 0; ht < 8; ++ht) wv[ht] = we[l15 + ht * 16];

        // GEMM + logit: wave w -> node tile [w*16, w*16+16)
        const int tb = w * 16;
        bf16x8 af[4];
        #pragma unroll
        for (int ks = 0; ks < 4; ++ks)
            af[ks] = *(const bf16x8*)(feb + (tb + l15) * 256 +
                                      (((ks * 4 + kg) * 16) ^ ((l15 & 7) << 4)));
        f32x4 acc[8];
        #pragma unroll
        for (int ht = 0; ht < 8; ++ht) acc[ht] = (f32x4){0.f, 0.f, 0.f, 0.f};
        #pragma unroll
        for (int ks = 0; ks < 4; ++ks) {
            #pragma unroll
            for (int ht = 0; ht < 8; ++ht) {
                bf16x8 bfr = *(const bf16x8*)(wuT + (size_t)(l15 + ht * 16) * DD + ks * 32 + kg * 8);
                acc[ht] = __builtin_amdgcn_mfma_f32_16x16x32_bf16(af[ks], bfr, acc[ht], 0, 0, 0);
            }
        }
        #pragma unroll
        for (int r = 0; r < 4; ++r) {
            int node = tb + kg * 4 + r;          // C layout: row=(lane>>4)*4+reg
            int gn = segl[node];
            const float* vg = vtab + (size_t)gn * DD + l15;
            float pp = 0.f;
            #pragma unroll
            for (int ht = 0; ht < 8; ++ht) {
                float x = acc[ht][r] + vg[ht * 16];
                float sg = 1.f / (1.f + __expf(-x));
                pp = fmaf(sg, wv[ht], pp);
            }
            pp += __shfl_xor(pp, 1);
            pp += __shfl_xor(pp, 2);
            pp += __shfl_xor(pp, 4);
            pp += __shfl_xor(pp, 8);
            if (l15 == 0)
                eel[node] = (n0 + node < N) ? ((pp != 0.f) ? __expf(pp) : pp) : 0.f;
        }
    }
    __syncthreads();

    // graph-parallel pooling from LDS (bf16 feats, fp32 accum) — verified serial form
    {
        const int gfirst = segl[0];
        const int glast  = segl[127];
        for (int g = gfirst + w; g <= glast; g += 8) {
            int go = offs[g];
            int gc = counts[g];
            int rbeg = go - n0;      rbeg = (rbeg > 0) ? rbeg : 0;
            int rend = go + gc - n0; rend = (rend < 128) ? rend : 128;
            bool complete = (go >= n0) && (go + gc <= n0 + 128);
            float ax = 0.f, ay = 0.f, dw = 0.f;
            for (int i = rbeg; i < rend; ++i) {
                float wi = eel[i];
                unsigned pv = *(const unsigned*)(feb + i * 256 + ((lane * 4) ^ ((i & 7) << 4)));
                dw += wi;
                ax = fmaf(bf2f((unsigned short)(pv & 0xffffu)), wi, ax);
                ay = fmaf(bf2f((unsigned short)(pv >> 16)), wi, ay);
            }
            if (complete) {
                float inv = 1.f / dw;
                *(float2*)&out[(size_t)g * DD + lane * 2] = make_float2(ax * inv, ay * inv);
            } else {
                int slot = (go >= n0) ? 0 : 1;
                *(float2*)&partial[(size_t)(g * 2 + slot) * DD + lane * 2] = make_float2(ax, ay);
                if (lane == 0) dens[g * 2 + slot] = dw;
            }
        }
    }
}

// ---------------- KD: combine the 2 partial slots of boundary-crossing graphs ----------------
__global__ __launch_bounds__(128)
void kd_combine(const float* __restrict__ partial, const float* __restrict__ dens,
                const int* __restrict__ offs, const int* __restrict__ counts,
                float* __restrict__ out, int B)
{
    int g = blockIdx.x;
    int off = offs[g], c = counts[g];
    if ((off >> 7) == ((off + c - 1) >> 7)) return;   // interior: already written by kc
    int d = threadIdx.x;
    float v = partial[(size_t)(g * 2) * DD + d] + partial[(size_t)(g * 2 + 1) * DD + d];
    float den = dens[g * 2] + dens[g * 2 + 1];
    out[(size_t)g * DD + d] = v / den;
}

extern "C" void kernel_launch(void* const* d_in, const int* in_sizes, int n_in,
                              void* d_out, int out_size, void* d_ws, size_t ws_size,
                              hipStream_t stream)
{
    const float* feats  = (const float*)d_in[0];
    const float* Wu     = (const float*)d_in[1];
    const float* Wv     = (const float*)d_in[2];
    const float* bv     = (const float*)d_in[3];
    const float* we     = (const float*)d_in[4];
    const int*   seg    = (const int*)d_in[5];
    const int*   counts = (const int*)d_in[6];
    const int N = in_sizes[0] / DD;
    const int B = in_sizes[6];

    char* w = (char*)d_ws;
    int*   offs = (int*)w;    w += ((size_t)B * sizeof(int) + 255) & ~(size_t)255;
    float* mean = (float*)w;  w += (size_t)B * DD * sizeof(float);
    float* amax = (float*)w;  w += (size_t)B * DD * sizeof(float);
    float* vtab = (float*)w;  w += (size_t)B * DD * sizeof(float);
    short* wuT  = (short*)w;  w += (size_t)DD * DD * sizeof(short);
    float* dens = (float*)w;  w += (size_t)B * 2 * sizeof(float);
    // partial pooled vectors alias mean+amax (dead after k2): 2*B*DD floats
    float* partial = mean;

    k0_combined<<<65, 256, 0, stream>>>(counts, offs, B, Wu, wuT);
    k1_stats<<<B, 256, 0, stream>>>(feats, offs, counts, mean, amax);
    k2_vtab<<<(B + 15) / 16, 128, 0, stream>>>(mean, amax, Wv, bv, vtab, B);

    const int blocks = (N + 127) / 128;
    kc_v4<<<blocks, 512, 0, stream>>>(feats, wuT, vtab, we, seg, offs, counts,
                                      partial, dens, (float*)d_out, N);
    kd_combine<<<B, 128, 0, stream>>>(partial, dens, offs, counts, (float*)d_out, B);
}

// Round 13
// 257.370 us; speedup vs baseline: 1.0823x; 1.0639x over previous
//
#include <hip/hip_runtime.h>
#include <hip/hip_bf16.h>
#include <math.h>

#define DD 128

typedef __attribute__((ext_vector_type(8))) short bf16x8;
typedef __attribute__((ext_vector_type(4))) float f32x4;

static __device__ __forceinline__ short f2bf(float x) {
    union { float f; unsigned u; } v; v.f = x;
    unsigned r = v.u + 0x7FFFu + ((v.u >> 16) & 1u);   // RNE
    return (short)(r >> 16);
}
static __device__ __forceinline__ float bf2f(unsigned short h) {
    union { unsigned u; float f; } v; v.u = ((unsigned)h) << 16;
    return v.f;
}
// pack 2 f32 -> 2 bf16 (RNE), dst = bf(lo) | bf(hi)<<16
static __device__ __forceinline__ unsigned cvtpk(float lo, float hi) {
    unsigned r;
    asm("v_cvt_pk_bf16_f32 %0, %1, %2" : "=v"(r) : "v"(lo), "v"(hi));
    return r;
}

// ---------------- K0: block 0 = prefix scan; blocks 1..64 = WuT bf16 prep ----------------
__global__ void k0_combined(const int* __restrict__ counts, int* __restrict__ offs, int B,
                            const float* __restrict__ Wu, short* __restrict__ wuT)
{
    if (blockIdx.x == 0) {
        __shared__ int part[256];
        int t = threadIdx.x;
        int chunk = (B + 255) >> 8;
        int s = 0;
        for (int i = 0; i < chunk; ++i) {
            int idx = t * chunk + i;
            if (idx < B) s += counts[idx];
        }
        part[t] = s;
        __syncthreads();
        for (int off = 1; off < 256; off <<= 1) {
            int val = (t >= off) ? part[t - off] : 0;
            __syncthreads();
            part[t] += val;
            __syncthreads();
        }
        int run = (t > 0) ? part[t - 1] : 0;
        for (int i = 0; i < chunk; ++i) {
            int idx = t * chunk + i;
            if (idx < B) { offs[idx] = run; run += counts[idx]; }
        }
    } else {
        int idx = (blockIdx.x - 1) * 256 + threadIdx.x;   // 0..16383
        int h = idx >> 7, k = idx & 127;
        wuT[(size_t)h * DD + k] = f2bf(Wu[(size_t)k * DD + h]);
    }
}

// ---------------- K1: per-graph mean + absmax (float4 lanes, 8-row stripe) ----------------
__global__ __launch_bounds__(256)
void k1_stats(const float* __restrict__ feats, const int* __restrict__ offs,
              const int* __restrict__ counts, float* __restrict__ mean,
              float* __restrict__ amax)
{
    int g = blockIdx.x;
    int s = offs[g], c = counts[g];
    int t = threadIdx.x;
    int col = (t & 31) * 4;          // float4 column
    int r0 = t >> 5;                 // 0..7
    float4 sm = {0.f, 0.f, 0.f, 0.f};
    float4 mx = {0.f, 0.f, 0.f, 0.f};
    const float* base = feats + (size_t)s * DD + col;
    #pragma unroll 4
    for (int i = r0; i < c; i += 8) {
        float4 v = *(const float4*)(base + (size_t)i * DD);
        sm.x += v.x; sm.y += v.y; sm.z += v.z; sm.w += v.w;
        mx.x = fmaxf(mx.x, fabsf(v.x)); mx.y = fmaxf(mx.y, fabsf(v.y));
        mx.z = fmaxf(mx.z, fabsf(v.z)); mx.w = fmaxf(mx.w, fabsf(v.w));
    }
    __shared__ float ls[8][DD];
    __shared__ float lm[8][DD];
    *(float4*)&ls[r0][col] = sm;
    *(float4*)&lm[r0][col] = mx;
    __syncthreads();
    if (t < DD) {
        float ss = 0.f, mm = 0.f;
        #pragma unroll
        for (int r = 0; r < 8; ++r) {
            ss += ls[r][t];
            mm = fmaxf(mm, lm[r][t]);
        }
        mean[(size_t)g * DD + t] = ss / (float)c;
        amax[(size_t)g * DD + t] = mm;
    }
}

// ---------------- K2: vtab[g] = row(g) @ W_v + b_v ----------------
// row(g) = (g odd) ? amax[g/2] : mean[g/2]   (torch interleaved-table quirk)
__global__ __launch_bounds__(128)
void k2_vtab(const float* __restrict__ mean, const float* __restrict__ amax,
             const float* __restrict__ Wv, const float* __restrict__ bv,
             float* __restrict__ vtab, int B)
{
    __shared__ float rows[16][DD];
    int g0 = blockIdx.x * 16;
    int h = threadIdx.x;
    for (int i = 0; i < 16; ++i) {
        int g = g0 + i;
        float val = 0.f;
        if (g < B) {
            int gg = g >> 1;
            const float* src = (g & 1) ? &amax[(size_t)gg * DD] : &mean[(size_t)gg * DD];
            val = src[h];
        }
        rows[i][h] = val;
    }
    __syncthreads();
    float acc[16];
    float bvh = bv[h];
    #pragma unroll
    for (int i = 0; i < 16; ++i) acc[i] = bvh;
    for (int d = 0; d < DD; d += 2) {
        float w0 = Wv[(size_t)d * DD + h];
        float w1 = Wv[(size_t)(d + 1) * DD + h];
        #pragma unroll
        for (int i = 0; i < 16; ++i) {
            float2 r = *(const float2*)&rows[i][d];
            acc[i] = fmaf(r.x, w0, acc[i]);
            acc[i] = fmaf(r.y, w1, acc[i]);
        }
    }
    #pragma unroll
    for (int i = 0; i < 16; ++i) {
        int g = g0 + i;
        if (g < B) vtab[(size_t)g * DD + h] = acc[i];
    }
}

// ---------------- KC: flat fused GEMM + logit + graph-parallel pooling ----------------
// 128 nodes/block, 512 threads (8 waves, ONE 16-node MFMA tile each).
// launch_bounds(512,6): ~85 VGPR budget -> no spill (r12's (512,8) forced 64 and
// spilled ~86MB scratch). Pooling loop is the twice-verified serial form.
__global__ __launch_bounds__(512, 6)
void kc_v5(const float* __restrict__ feats, const short* __restrict__ wuT,
           const float* __restrict__ vtab, const float* __restrict__ we,
           const int* __restrict__ seg, const int* __restrict__ offs,
           const int* __restrict__ counts,
           float* __restrict__ partial, float* __restrict__ dens,
           float* __restrict__ out, int N)
{
    __shared__ short fe[128 * DD];   // 32 KB swizzled bf16 [row][128]
    __shared__ float eel[128];
    __shared__ int   segl[128];
    char* feb = (char*)fe;
    const int t = threadIdx.x;
    const int bid = blockIdx.x;
    const int n0 = bid << 7;

    if (t < 128) {
        int n = n0 + t;
        segl[t] = seg[(n < N) ? n : (N - 1)];
    }

    // stage: 2048 x 16B bf16 chunks, 4 per thread, fully unrolled
    #pragma unroll
    for (int it = 0; it < 4; ++it) {
        int ch = it * 512 + t;
        int row = ch >> 4, sub = ch & 15;
        int n = n0 + row;
        uint4 uv;
        if (n < N) {
            const float4* gp = (const float4*)(feats + (size_t)n * DD + sub * 8);
            float4 a = gp[0], b = gp[1];
            uv.x = cvtpk(a.x, a.y);
            uv.y = cvtpk(a.z, a.w);
            uv.z = cvtpk(b.x, b.y);
            uv.w = cvtpk(b.z, b.w);
        } else {
            uv = (uint4){0u, 0u, 0u, 0u};
        }
        *(uint4*)(feb + row * 256 + ((sub * 16) ^ ((row & 7) << 4))) = uv;
    }
    __syncthreads();

    const int w = t >> 6, lane = t & 63;
    const int l15 = lane & 15, kg = lane >> 4;

    {
        float wv[8];
        #pragma unroll
        for (int ht = 0; ht < 8; ++ht) wv[ht] = we[l15 + ht * 16];

        // GEMM + logit: wave w -> node tile [w*16, w*16+16)
        const int tb = w * 16;
        bf16x8 af[4];
        #pragma unroll
        for (int ks = 0; ks < 4; ++ks)
            af[ks] = *(const bf16x8*)(feb + (tb + l15) * 256 +
                                      (((ks * 4 + kg) * 16) ^ ((l15 & 7) << 4)));
        f32x4 acc[8];
        #pragma unroll
        for (int ht = 0; ht < 8; ++ht) acc[ht] = (f32x4){0.f, 0.f, 0.f, 0.f};
        #pragma unroll
        for (int ks = 0; ks < 4; ++ks) {
            #pragma unroll
            for (int ht = 0; ht < 8; ++ht) {
                bf16x8 bfr = *(const bf16x8*)(wuT + (size_t)(l15 + ht * 16) * DD + ks * 32 + kg * 8);
                acc[ht] = __builtin_amdgcn_mfma_f32_16x16x32_bf16(af[ks], bfr, acc[ht], 0, 0, 0);
            }
        }
        #pragma unroll
        for (int r = 0; r < 4; ++r) {
            int node = tb + kg * 4 + r;          // C layout: row=(lane>>4)*4+reg
            int gn = segl[node];
            const float* vg = vtab + (size_t)gn * DD + l15;
            float pp = 0.f;
            #pragma unroll
            for (int ht = 0; ht < 8; ++ht) {
                float x = acc[ht][r] + vg[ht * 16];
                float sg = 1.f / (1.f + __expf(-x));
                pp = fmaf(sg, wv[ht], pp);
            }
            pp += __shfl_xor(pp, 1);
            pp += __shfl_xor(pp, 2);
            pp += __shfl_xor(pp, 4);
            pp += __shfl_xor(pp, 8);
            if (l15 == 0)
                eel[node] = (n0 + node < N) ? ((pp != 0.f) ? __expf(pp) : pp) : 0.f;
        }
    }
    __syncthreads();

    // graph-parallel pooling from LDS (bf16 feats, fp32 accum) — verified serial form
    {
        const int gfirst = segl[0];
        const int glast  = segl[127];
        for (int g = gfirst + w; g <= glast; g += 8) {
            int go = offs[g];
            int gc = counts[g];
            int rbeg = go - n0;      rbeg = (rbeg > 0) ? rbeg : 0;
            int rend = go + gc - n0; rend = (rend < 128) ? rend : 128;
            bool complete = (go >= n0) && (go + gc <= n0 + 128);
            float ax = 0.f, ay = 0.f, dw = 0.f;
            for (int i = rbeg; i < rend; ++i) {
                float wi = eel[i];
                unsigned pv = *(const unsigned*)(feb + i * 256 + ((lane * 4) ^ ((i & 7) << 4)));
                dw += wi;
                ax = fmaf(bf2f((unsigned short)(pv & 0xffffu)), wi, ax);
                ay = fmaf(bf2f((unsigned short)(pv >> 16)), wi, ay);
            }
            if (complete) {
                float inv = 1.f / dw;
                *(float2*)&out[(size_t)g * DD + lane * 2] = make_float2(ax * inv, ay * inv);
            } else {
                int slot = (go >= n0) ? 0 : 1;
                *(float2*)&partial[(size_t)(g * 2 + slot) * DD + lane * 2] = make_float2(ax, ay);
                if (lane == 0) dens[g * 2 + slot] = dw;
            }
        }
    }
}

// ---------------- KD: combine the 2 partial slots of boundary-crossing graphs ----------------
__global__ __launch_bounds__(128)
void kd_combine(const float* __restrict__ partial, const float* __restrict__ dens,
                const int* __restrict__ offs, const int* __restrict__ counts,
                float* __restrict__ out, int B)
{
    int g = blockIdx.x;
    int off = offs[g], c = counts[g];
    if ((off >> 7) == ((off + c - 1) >> 7)) return;   // interior: already written by kc
    int d = threadIdx.x;
    float v = partial[(size_t)(g * 2) * DD + d] + partial[(size_t)(g * 2 + 1) * DD + d];
    float den = dens[g * 2] + dens[g * 2 + 1];
    out[(size_t)g * DD + d] = v / den;
}

extern "C" void kernel_launch(void* const* d_in, const int* in_sizes, int n_in,
                              void* d_out, int out_size, void* d_ws, size_t ws_size,
                              hipStream_t stream)
{
    const float* feats  = (const float*)d_in[0];
    const float* Wu     = (const float*)d_in[1];
    const float* Wv     = (const float*)d_in[2];
    const float* bv     = (const float*)d_in[3];
    const float* we     = (const float*)d_in[4];
    const int*   seg    = (const int*)d_in[5];
    const int*   counts = (const int*)d_in[6];
    const int N = in_sizes[0] / DD;
    const int B = in_sizes[6];

    char* w = (char*)d_ws;
    int*   offs = (int*)w;    w += ((size_t)B * sizeof(int) + 255) & ~(size_t)255;
    float* mean = (float*)w;  w += (size_t)B * DD * sizeof(float);
    float* amax = (float*)w;  w += (size_t)B * DD * sizeof(float);
    float* vtab = (float*)w;  w += (size_t)B * DD * sizeof(float);
    short* wuT  = (short*)w;  w += (size_t)DD * DD * sizeof(short);
    float* dens = (float*)w;  w += (size_t)B * 2 * sizeof(float);
    // partial pooled vectors alias mean+amax (dead after k2): 2*B*DD floats
    float* partial = mean;

    k0_combined<<<65, 256, 0, stream>>>(counts, offs, B, Wu, wuT);
    k1_stats<<<B, 256, 0, stream>>>(feats, offs, counts, mean, amax);
    k2_vtab<<<(B + 15) / 16, 128, 0, stream>>>(mean, amax, Wv, bv, vtab, B);

    const int blocks = (N + 127) / 128;
    kc_v5<<<blocks, 512, 0, stream>>>(feats, wuT, vtab, we, seg, offs, counts,
                                      partial, dens, (float*)d_out, N);
    kd_combine<<<B, 128, 0, stream>>>(partial, dens, offs, counts, (float*)d_out, B);
}